// Round 5
// baseline (4495.589 us; speedup 1.0000x reference)
//
#include <hip/hip_runtime.h>
#include <algorithm>
#include <cstdint>

// Problem constants (fixed by setup_inputs)
#define Nn 8192
#define Mm 8192
#define Dd 512
#define Cc 128

#define BT 128   // block tile (n and m)
#define TK 16    // k-chunk

// ---- workspace layout (bytes) ----
// Empirical (R4): ws_size < ~302 MB -> no full-matrix store path. Recompute
// design only. Candidates are uint2{f32 key bits, packed idx} = 8 B.
#define WS_SR     0ull            // double[8192]
#define WS_SC     65536ull        // double[8192]
#define WS_GHIST  131072ull       // uint[65536]
#define WS_CTR    393216ull       // uint[16]
#define WS_FINAL  393280ull       // uint2[4096]
#define WS_CAND   426048ull       // uint2[cap]
#define FCAP      4096u

// Column mapping: thread tx owns cols {tx*4..+3} and {64+tx*4..+3} ->
// SB b128 fragment reads are 2-way bank aliased (free, m136).
__device__ __forceinline__ int jcol(int tx, int j) {
  return (j < 4) ? tx * 4 + j : 64 + tx * 4 + (j - 4);
}

// ---------------------------------------------------------------------------
// Inner GEMM (256 thr, 8x8/thread) with TWO-LEVEL accumulation, i-split into
// two 4x8 halves per chunk so acc1 is 32 not 64 regs. Per-element op chain is
// bitwise identical to the R1/R2-validated kernels: zero-init 16-fma chain per
// 16-k chunk (kk order), then one add into acc2, chunks in order — the i-split
// only reorders *independent* per-element chains, never an element's own ops.
// ---------------------------------------------------------------------------
__device__ __forceinline__ void inner_gemm(const float* __restrict__ A,
                                           const float* __restrict__ B,
                                           int n0, int m0, int tid,
                                           float (*SA)[BT], float (*SB)[BT],
                                           float acc2[8][8]) {
  const int tx = tid & 15, ty = tid >> 4;
  const int lrow = tid >> 1;       // 0..127 staging column
  const int lk8  = (tid & 1) * 8;  // 0 or 8 staging k-offset
  const float* Ap = A + (size_t)(n0 + lrow) * Dd + lk8;
  const float* Bp = B + (size_t)(m0 + lrow) * Dd + lk8;

#pragma unroll
  for (int i = 0; i < 8; ++i)
#pragma unroll
    for (int j = 0; j < 8; ++j) acc2[i][j] = 0.0f;

  float4 pa0 = *(const float4*)(Ap);
  float4 pa1 = *(const float4*)(Ap + 4);
  float4 pb0 = *(const float4*)(Bp);
  float4 pb1 = *(const float4*)(Bp + 4);

  for (int k0 = 0; k0 < Dd; k0 += TK) {
    __syncthreads();
    {
      const float ar[8] = {pa0.x,pa0.y,pa0.z,pa0.w,pa1.x,pa1.y,pa1.z,pa1.w};
      const float br[8] = {pb0.x,pb0.y,pb0.z,pb0.w,pb1.x,pb1.y,pb1.z,pb1.w};
#pragma unroll
      for (int s = 0; s < 8; ++s) { SA[lk8 + s][lrow] = ar[s]; SB[lk8 + s][lrow] = br[s]; }
    }
    if (k0 + TK < Dd) {  // prefetch next chunk; flies during compute
      pa0 = *(const float4*)(Ap + k0 + TK);
      pa1 = *(const float4*)(Ap + k0 + TK + 4);
      pb0 = *(const float4*)(Bp + k0 + TK);
      pb1 = *(const float4*)(Bp + k0 + TK + 4);
    }
    __syncthreads();
#pragma unroll
    for (int h = 0; h < 2; ++h) {
      float t[4][8];
#pragma unroll
      for (int i = 0; i < 4; ++i)
#pragma unroll
        for (int j = 0; j < 8; ++j) t[i][j] = 0.0f;
#pragma unroll
      for (int kk = 0; kk < TK; ++kk) {
        const float4 av  = *(const float4*)&SA[kk][ty * 8 + h * 4];
        const float4 bv0 = *(const float4*)&SB[kk][tx * 4];
        const float4 bv1 = *(const float4*)&SB[kk][64 + tx * 4];
        const float a[4] = {av.x, av.y, av.z, av.w};
        const float b[8] = {bv0.x,bv0.y,bv0.z,bv0.w,bv1.x,bv1.y,bv1.z,bv1.w};
#pragma unroll
        for (int i = 0; i < 4; ++i)
#pragma unroll
          for (int j = 0; j < 8; ++j) t[i][j] = fmaf(a[i], b[j], t[i][j]);
      }
#pragma unroll
      for (int i = 0; i < 4; ++i)
#pragma unroll
        for (int j = 0; j < 8; ++j) acc2[h * 4 + i][j] += t[i][j];
    }
  }
}

// ---------------------------------------------------------------------------
// Overlap GEMM (cas0:[C][N] x cas1:[C][M]), same i-split two-level structure.
// Staging is flat lane-linear float4 (baseline-free LDS bank pattern, fully
// coalesced global reads).
// ---------------------------------------------------------------------------
__device__ __forceinline__ void ov_gemm(const float* __restrict__ C0,
                                        const float* __restrict__ C1,
                                        int n0, int m0, int tid,
                                        float (*SA)[BT], float (*SB)[BT],
                                        float ov2[8][8]) {
  const int tx = tid & 15, ty = tid >> 4;
  const int fc = tid >> 5;          // 0..7 c-row
  const int fn = (tid & 31) * 4;    // 0..124 n-col
  const float* c0a = C0 + (size_t)fc * Nn + n0 + fn;
  const float* c0b = C0 + (size_t)(fc + 8) * Nn + n0 + fn;
  const float* c1a = C1 + (size_t)fc * Mm + m0 + fn;
  const float* c1b = C1 + (size_t)(fc + 8) * Mm + m0 + fn;

#pragma unroll
  for (int i = 0; i < 8; ++i)
#pragma unroll
    for (int j = 0; j < 8; ++j) ov2[i][j] = 0.0f;

  float4 pa0 = *(const float4*)c0a;
  float4 pa1 = *(const float4*)c0b;
  float4 pb0 = *(const float4*)c1a;
  float4 pb1 = *(const float4*)c1b;

  for (int c0i = 0; c0i < Cc; c0i += TK) {
    __syncthreads();
    *(float4*)&SA[fc][fn]     = pa0;
    *(float4*)&SA[fc + 8][fn] = pa1;
    *(float4*)&SB[fc][fn]     = pb0;
    *(float4*)&SB[fc + 8][fn] = pb1;
    if (c0i + TK < Cc) {
      pa0 = *(const float4*)(c0a + (size_t)(c0i + TK) * Nn);
      pa1 = *(const float4*)(c0b + (size_t)(c0i + TK) * Nn);
      pb0 = *(const float4*)(c1a + (size_t)(c0i + TK) * Mm);
      pb1 = *(const float4*)(c1b + (size_t)(c0i + TK) * Mm);
    }
    __syncthreads();
#pragma unroll
    for (int h = 0; h < 2; ++h) {
      float t[4][8];
#pragma unroll
      for (int i = 0; i < 4; ++i)
#pragma unroll
        for (int j = 0; j < 8; ++j) t[i][j] = 0.0f;
#pragma unroll
      for (int kk = 0; kk < TK; ++kk) {
        const float4 av  = *(const float4*)&SA[kk][ty * 8 + h * 4];
        const float4 bv0 = *(const float4*)&SB[kk][tx * 4];
        const float4 bv1 = *(const float4*)&SB[kk][64 + tx * 4];
        const float a[4] = {av.x, av.y, av.z, av.w};
        const float b[8] = {bv0.x,bv0.y,bv0.z,bv0.w,bv1.x,bv1.y,bv1.z,bv1.w};
#pragma unroll
        for (int i = 0; i < 4; ++i)
#pragma unroll
          for (int j = 0; j < 8; ++j) t[i][j] = fmaf(a[i], b[j], t[i][j]);
      }
#pragma unroll
      for (int i = 0; i < 4; ++i)
#pragma unroll
        for (int j = 0; j < 8; ++j) ov2[h * 4 + i][j] += t[i][j];
    }
  }
}

// ---------------------------------------------------------------------------
// Pass 1: inner GEMM -> exp row/col sums (f64), streaming epilogue.
// ~120 VGPR peak -> (256,3): 12 waves/CU, zero spill.
// ---------------------------------------------------------------------------
__global__ __launch_bounds__(256, 3) void k_pass1(const float* __restrict__ A,
                                                  const float* __restrict__ B,
                                                  double* __restrict__ Sr,
                                                  double* __restrict__ Sc) {
  __shared__ float SA[TK][BT];
  __shared__ float SB[TK][BT];
  __shared__ double csum[BT];
  const int tid = threadIdx.x;
  const int tx = tid & 15, ty = tid >> 4;
  const int n0 = blockIdx.y * BT, m0 = blockIdx.x * BT;

  float acc2[8][8];
  inner_gemm(A, B, n0, m0, tid, SA, SB, acc2);

  if (tid < BT) csum[tid] = 0.0;
  __syncthreads();

  float cp[8];
#pragma unroll
  for (int j = 0; j < 8; ++j) cp[j] = 0.0f;

#pragma unroll
  for (int i = 0; i < 8; ++i) {
    float r = 0.0f;
#pragma unroll
    for (int j = 0; j < 8; ++j) {
      const float e = expf(2.0f * acc2[i][j] - 2.0f);
      r += e;
      cp[j] += e;
    }
    double v = (double)r;
    v += __shfl_xor(v, 1, 16);
    v += __shfl_xor(v, 2, 16);
    v += __shfl_xor(v, 4, 16);
    v += __shfl_xor(v, 8, 16);
    if (tx == 0) atomicAdd(&Sr[n0 + ty * 8 + i], v);
  }
#pragma unroll
  for (int j = 0; j < 8; ++j) {
    double v = (double)cp[j];
    v += __shfl_xor(v, 16, 64);
    v += __shfl_xor(v, 32, 64);
    if ((tid & 63) < 16) atomicAdd(&csum[jcol(tx, j)], v);
  }
  __syncthreads();
  if (tid < BT) atomicAdd(&Sc[m0 + tid], csum[tid]);
}

// ---------------------------------------------------------------------------
__global__ void k_recip(double* __restrict__ Sr, double* __restrict__ Sc) {
  const int i = blockIdx.x * 256 + threadIdx.x;
  if (i < Nn) Sr[i] = 1.0 / Sr[i];
  if (i < Mm) Sc[i] = 1.0 / Sc[i];
}

// ---------------------------------------------------------------------------
// Pass 2: inner GEMM + overlap GEMM + f64 score -> f32 key, two-level
// histogram threshold + device-scope running bound, push uint2 candidates.
// invSr/invSc served from LDS (same f64 bits) to cut 32 VGPRs.
// ---------------------------------------------------------------------------
__global__ __launch_bounds__(256, 2) void k_pass2(
    const float* __restrict__ A, const float* __restrict__ B,
    const float* __restrict__ C0, const float* __restrict__ C1,
    const double* __restrict__ invSr, const double* __restrict__ invSc,
    uint2* __restrict__ cand, unsigned int* __restrict__ ctr, unsigned int cap) {
  __shared__ float SA[TK][BT];
  __shared__ float SB[TK][BT];
  __shared__ unsigned int h1[256];
  __shared__ unsigned int scn[256];
  __shared__ unsigned int sh_misc[4];
  const int tid = threadIdx.x;
  const int tx = tid & 15, ty = tid >> 4;
  const int n0 = blockIdx.y * BT, m0 = blockIdx.x * BT;

  float acc2[8][8];
  inner_gemm(A, B, n0, m0, tid, SA, SB, acc2);
  float ov2[8][8];
  ov_gemm(C0, C1, n0, m0, tid, SA, SB, ov2);

  // repurpose staging LDS for the f64 normalizers (bitwise-identical values)
  __syncthreads();
  double* dsr = (double*)(&SA[0][0]);   // 128 doubles
  double* dsc = (double*)(&SB[0][0]);   // 128 doubles
  if (tid < BT) { dsr[tid] = invSr[n0 + tid]; dsc[tid] = invSc[m0 + tid]; }
  __syncthreads();

  unsigned int sbits[8][8];
#pragma unroll
  for (int i = 0; i < 8; ++i)
#pragma unroll
    for (int j = 0; j < 8; ++j) {
      const double e = exp(2.0 * (double)acc2[i][j] - 2.0);
      const double s = e * e * dsr[ty * 8 + i] * dsc[jcol(tx, j)] * (double)ov2[i][j];
      sbits[i][j] = __float_as_uint((float)s);  // s > 0 -> monotone bits
    }

  // ---- two-level (8+8 bit) block histogram threshold ----
  h1[tid] = 0;
  __syncthreads();
#pragma unroll
  for (int i = 0; i < 8; ++i)
#pragma unroll
    for (int j = 0; j < 8; ++j) atomicAdd(&h1[sbits[i][j] >> 24], 1u);
  __syncthreads();
  if (tid == 0) {
    unsigned cum = 0, cb = 0, above = 0;
    for (int b = 255; b >= 0; --b) {
      const unsigned nc = cum + h1[b];
      if (nc >= 256u) { cb = (unsigned)b; above = cum; break; }
      cum = nc;
    }
    sh_misc[0] = cb; sh_misc[1] = above;
  }
  __syncthreads();
  const unsigned cb = sh_misc[0], above = sh_misc[1];
  __syncthreads();
  h1[tid] = 0;
  __syncthreads();
#pragma unroll
  for (int i = 0; i < 8; ++i)
#pragma unroll
    for (int j = 0; j < 8; ++j)
      if ((sbits[i][j] >> 24) == cb) atomicAdd(&h1[(sbits[i][j] >> 16) & 0xFFu], 1u);
  __syncthreads();
  if (tid == 0) {
    unsigned cum = above, tb = cb << 8;
    for (int b = 255; b >= 0; --b) {
      cum += h1[b];
      if (cum >= 256u) { tb = (cb << 8) | (unsigned)b; break; }
    }
    const unsigned old = atomicMax(&ctr[2], tb);  // device-scope running bound
    sh_misc[2] = tb > old ? tb : old;
  }
  __syncthreads();
  const unsigned tb16 = sh_misc[2];

  // ---- candidate push (block-aggregated offsets) ----
  unsigned cnt = 0;
#pragma unroll
  for (int i = 0; i < 8; ++i)
#pragma unroll
    for (int j = 0; j < 8; ++j) cnt += ((sbits[i][j] >> 16) >= tb16) ? 1u : 0u;
  scn[tid] = cnt;
  __syncthreads();
  if (tid == 0) {
    unsigned run = 0;
    for (int t = 0; t < 256; ++t) { const unsigned c = scn[t]; scn[t] = run; run += c; }
    sh_misc[3] = atomicAdd(&ctr[0], run);
  }
  __syncthreads();
  unsigned pos = sh_misc[3] + scn[tid];
#pragma unroll
  for (int i = 0; i < 8; ++i)
#pragma unroll
    for (int j = 0; j < 8; ++j) {
      if ((sbits[i][j] >> 16) >= tb16) {
        if (pos < cap) {
          const unsigned idxv = ((unsigned)(n0 + ty * 8 + i) << 13) | (unsigned)(m0 + jcol(tx, j));
          cand[pos] = make_uint2(sbits[i][j], idxv);
        }
        ++pos;
      }
    }
}

// ---------------------------------------------------------------------------
__global__ void k_ghist(const uint2* __restrict__ cand,
                        const unsigned int* __restrict__ ctr,
                        unsigned int cap, unsigned int* __restrict__ ghist) {
  const unsigned n = min(ctr[0], cap);
  const unsigned stride = gridDim.x * blockDim.x;
  for (unsigned i = blockIdx.x * blockDim.x + threadIdx.x; i < n; i += stride)
    atomicAdd(&ghist[cand[i].x >> 16], 1u);
}

__global__ __launch_bounds__(256) void k_thresh(const unsigned int* __restrict__ ghist,
                                                unsigned int* __restrict__ ctr) {
  __shared__ unsigned int gsum[256];
  const int tid = threadIdx.x;
  unsigned s = 0;
  const int base = tid * 256;
  for (int b = 0; b < 256; ++b) s += ghist[base + b];
  gsum[tid] = s;
  __syncthreads();
  if (tid == 0) {
    unsigned cum = 0, g = 0, above = 0;
    for (int t = 255; t >= 0; --t) {
      const unsigned nc = cum + gsum[t];
      if (nc >= 256u) { g = (unsigned)t; above = cum; break; }
      cum = nc;
    }
    unsigned tb = g * 256u, c2 = above;
    for (int b = (int)g * 256 + 255; b >= (int)g * 256; --b) {
      c2 += ghist[b];
      if (c2 >= 256u) { tb = (unsigned)b; break; }
    }
    ctr[3] = tb;
  }
}

__global__ void k_collect(const uint2* __restrict__ cand,
                          unsigned int* __restrict__ ctr,
                          unsigned int cap, uint2* __restrict__ fin) {
  const unsigned n = min(ctr[0], cap);
  const unsigned tb = ctr[3];
  const unsigned stride = gridDim.x * blockDim.x;
  for (unsigned i = blockIdx.x * blockDim.x + threadIdx.x; i < n; i += stride) {
    const uint2 c = cand[i];
    if ((c.x >> 16) >= tb) {
      const unsigned p = atomicAdd(&ctr[1], 1u);
      if (p < FCAP) fin[p] = c;
    }
  }
}

// ---------------------------------------------------------------------------
// Sort: pack (key, ~idx) into u64, bitonic desc -> (key desc, idx asc),
// which is exactly lax.top_k / np tie semantics on the f32 scores.
// ---------------------------------------------------------------------------
__global__ __launch_bounds__(256) void k_sort(const uint2* __restrict__ fin,
                                              const unsigned int* __restrict__ ctr,
                                              float* __restrict__ out) {
  __shared__ unsigned long long kk[FCAP];
  const int tid = threadIdx.x;
  const unsigned n = min(ctr[1], FCAP);
  unsigned np2 = 256;
  while (np2 < n) np2 <<= 1;
  for (unsigned i = tid; i < np2; i += 256) {
    if (i < n) {
      const uint2 c = fin[i];
      kk[i] = ((unsigned long long)c.x << 32) | (unsigned long long)(c.y ^ 0xFFFFFFFFu);
    } else {
      kk[i] = 0ull;
    }
  }
  __syncthreads();
  for (unsigned k2 = 2; k2 <= np2; k2 <<= 1) {
    for (unsigned j = k2 >> 1; j > 0; j >>= 1) {
      for (unsigned i = tid; i < np2; i += 256) {
        const unsigned l = i ^ j;
        if (l > i) {
          const unsigned long long ka = kk[i], kb = kk[l];
          const bool aBefore = ka > kb;
          const bool dsc = (i & k2) == 0;
          const bool sw = dsc ? !aBefore : aBefore;
          if (sw) { kk[i] = kb; kk[l] = ka; }
        }
      }
      __syncthreads();
    }
  }
  {
    const unsigned long long kv = kk[tid];
    const unsigned key = (unsigned)(kv >> 32);
    const unsigned ix  = ((unsigned)kv) ^ 0xFFFFFFFFu;
    out[tid]        = (float)(ix >> 13);      // ref_corr_indices
    out[256 + tid]  = (float)(ix & 8191u);    // src_corr_indices
    out[512 + tid]  = __uint_as_float(key);   // corr_scores (same f32 bits)
  }
}

// ---------------------------------------------------------------------------
extern "C" void kernel_launch(void* const* d_in, const int* in_sizes, int n_in,
                              void* d_out, int out_size, void* d_ws, size_t ws_size,
                              hipStream_t stream) {
  (void)in_sizes; (void)n_in; (void)out_size;
  const float* ref = (const float*)d_in[0];
  const float* src = (const float*)d_in[1];
  const float* c0  = (const float*)d_in[2];
  const float* c1  = (const float*)d_in[3];
  char* ws = (char*)d_ws;
  double* Sr = (double*)(ws + WS_SR);
  double* Sc = (double*)(ws + WS_SC);
  unsigned int* ghist = (unsigned int*)(ws + WS_GHIST);
  unsigned int* ctr   = (unsigned int*)(ws + WS_CTR);
  uint2* fin  = (uint2*)(ws + WS_FINAL);
  uint2* cand = (uint2*)(ws + WS_CAND);
  const unsigned int cap = (ws_size > WS_CAND + 8)
      ? (unsigned int)std::min<size_t>((ws_size - WS_CAND) / 8, (size_t)(16u << 20))
      : 0u;

  hipMemsetAsync(d_ws, 0, (size_t)WS_FINAL, stream);  // Sr, Sc, ghist, ctr

  dim3 grid(Mm / BT, Nn / BT);
  k_pass1<<<grid, 256, 0, stream>>>(ref, src, Sr, Sc);
  k_recip<<<32, 256, 0, stream>>>(Sr, Sc);
  k_pass2<<<grid, 256, 0, stream>>>(ref, src, c0, c1, Sr, Sc, cand, ctr, cap);
  k_ghist<<<256, 256, 0, stream>>>(cand, ctr, cap, ghist);
  k_thresh<<<1, 256, 0, stream>>>(ghist, ctr);
  k_collect<<<256, 256, 0, stream>>>(cand, ctr, cap, fin);
  k_sort<<<1, 256, 0, stream>>>(fin, ctr, (float*)d_out);
}

// Round 6
// 2555.690 us; speedup vs baseline: 1.7591x; 1.7591x over previous
//
#include <hip/hip_runtime.h>
#include <algorithm>
#include <cstdint>

// Problem constants (fixed by setup_inputs)
#define Nn 8192
#define Mm 8192
#define Dd 512
#define Cc 128

#define BT  128  // pass1 tile (n and m); pass2 n-tile
#define BM2 64   // pass2 m-tile (8x4/thread keeps live regs < 128 -> no spill)
#define TK  16   // k-chunk (load-bearing for numerics; do not change)

// ---- workspace layout (bytes) ----
#define WS_SR    0ull         // double[8192]
#define WS_SC    65536ull     // double[8192]
#define WS_CTR   131072ull    // uint[16]: 0=cand_n 1=fin_n 2=run_tb16 3=tb16 4=cbin 5=above
#define WS_GHC   131136ull    // uint[256] coarse hist
#define WS_GHF   132160ull    // uint[256] fine hist
#define WS_FINAL 133184ull    // uint2[4096]
#define WS_CAND  165952ull    // uint2[cap]
#define FCAP     4096u

// Column mapping (pass1, 8 cols): thread tx owns {tx*4..+3} and {64+tx*4..+3}
// -> SB b128 fragment reads are 2-way bank aliased (free, m136).
__device__ __forceinline__ int jcol(int tx, int j) {
  return (j < 4) ? tx * 4 + j : 64 + tx * 4 + (j - 4);
}
// pass2 (4 cols over 64): {tx*2, tx*2+1, 32+tx*2, 32+tx*2+1}
__device__ __forceinline__ int jcol4(int tx, int j) {
  return (j < 2) ? tx * 2 + j : 32 + tx * 2 + (j - 2);
}

// ---------------------------------------------------------------------------
// Pass-1 inner GEMM (256 thr, 8x8/thread), two-level accumulation with i-split
// (acc1 is 32 regs). Per-element op chain identical to all validated rounds:
// fresh 16-fma chain per 16-k chunk (kk order), one add into acc2, chunks in
// order. Validated bitwise by R4/R5 absmax=0.
// ---------------------------------------------------------------------------
__device__ __forceinline__ void inner_gemm(const float* __restrict__ A,
                                           const float* __restrict__ B,
                                           int n0, int m0, int tid,
                                           float (*SA)[BT], float (*SB)[BT],
                                           float acc2[8][8]) {
  const int tx = tid & 15, ty = tid >> 4;
  const int lrow = tid >> 1;       // 0..127
  const int lk8  = (tid & 1) * 8;  // 0 or 8
  const float* Ap = A + (size_t)(n0 + lrow) * Dd + lk8;
  const float* Bp = B + (size_t)(m0 + lrow) * Dd + lk8;

#pragma unroll
  for (int i = 0; i < 8; ++i)
#pragma unroll
    for (int j = 0; j < 8; ++j) acc2[i][j] = 0.0f;

  float4 pa0 = *(const float4*)(Ap);
  float4 pa1 = *(const float4*)(Ap + 4);
  float4 pb0 = *(const float4*)(Bp);
  float4 pb1 = *(const float4*)(Bp + 4);

  for (int k0 = 0; k0 < Dd; k0 += TK) {
    __syncthreads();
    {
      const float ar[8] = {pa0.x,pa0.y,pa0.z,pa0.w,pa1.x,pa1.y,pa1.z,pa1.w};
      const float br[8] = {pb0.x,pb0.y,pb0.z,pb0.w,pb1.x,pb1.y,pb1.z,pb1.w};
#pragma unroll
      for (int s = 0; s < 8; ++s) { SA[lk8 + s][lrow] = ar[s]; SB[lk8 + s][lrow] = br[s]; }
    }
    if (k0 + TK < Dd) {  // prefetch flies during compute
      pa0 = *(const float4*)(Ap + k0 + TK);
      pa1 = *(const float4*)(Ap + k0 + TK + 4);
      pb0 = *(const float4*)(Bp + k0 + TK);
      pb1 = *(const float4*)(Bp + k0 + TK + 4);
    }
    __syncthreads();
#pragma unroll
    for (int h = 0; h < 2; ++h) {
      float t[4][8];
#pragma unroll
      for (int i = 0; i < 4; ++i)
#pragma unroll
        for (int j = 0; j < 8; ++j) t[i][j] = 0.0f;
#pragma unroll
      for (int kk = 0; kk < TK; ++kk) {
        const float4 av  = *(const float4*)&SA[kk][ty * 8 + h * 4];
        const float4 bv0 = *(const float4*)&SB[kk][tx * 4];
        const float4 bv1 = *(const float4*)&SB[kk][64 + tx * 4];
        const float a[4] = {av.x, av.y, av.z, av.w};
        const float b[8] = {bv0.x,bv0.y,bv0.z,bv0.w,bv1.x,bv1.y,bv1.z,bv1.w};
#pragma unroll
        for (int i = 0; i < 4; ++i)
#pragma unroll
          for (int j = 0; j < 8; ++j) t[i][j] = fmaf(a[i], b[j], t[i][j]);
      }
#pragma unroll
      for (int i = 0; i < 4; ++i)
#pragma unroll
        for (int j = 0; j < 8; ++j) acc2[h * 4 + i][j] += t[i][j];
    }
  }
}

// ---------------------------------------------------------------------------
// Pass 1: inner GEMM -> exp row/col sums (f64). (256,3): ~125 live regs < 170.
// ---------------------------------------------------------------------------
__global__ __launch_bounds__(256, 3) void k_pass1(const float* __restrict__ A,
                                                  const float* __restrict__ B,
                                                  double* __restrict__ Sr,
                                                  double* __restrict__ Sc) {
  __shared__ float SA[TK][BT];
  __shared__ float SB[TK][BT];
  __shared__ double csum[BT];
  const int tid = threadIdx.x;
  const int tx = tid & 15, ty = tid >> 4;
  const int n0 = blockIdx.y * BT, m0 = blockIdx.x * BT;

  float acc2[8][8];
  inner_gemm(A, B, n0, m0, tid, SA, SB, acc2);

  if (tid < BT) csum[tid] = 0.0;
  __syncthreads();

  float cp[8];
#pragma unroll
  for (int j = 0; j < 8; ++j) cp[j] = 0.0f;

#pragma unroll
  for (int i = 0; i < 8; ++i) {
    float r = 0.0f;
#pragma unroll
    for (int j = 0; j < 8; ++j) {
      const float e = expf(2.0f * acc2[i][j] - 2.0f);
      r += e;
      cp[j] += e;
    }
    double v = (double)r;
    v += __shfl_xor(v, 1, 16);
    v += __shfl_xor(v, 2, 16);
    v += __shfl_xor(v, 4, 16);
    v += __shfl_xor(v, 8, 16);
    if (tx == 0) atomicAdd(&Sr[n0 + ty * 8 + i], v);
  }
#pragma unroll
  for (int j = 0; j < 8; ++j) {
    double v = (double)cp[j];
    v += __shfl_xor(v, 16, 64);
    v += __shfl_xor(v, 32, 64);
    if ((tid & 63) < 16) atomicAdd(&csum[jcol(tx, j)], v);
  }
  __syncthreads();
  if (tid < BT) atomicAdd(&Sc[m0 + tid], csum[tid]);
}

// ---------------------------------------------------------------------------
__global__ void k_recip(double* __restrict__ Sr, double* __restrict__ Sc) {
  const int i = blockIdx.x * 256 + threadIdx.x;
  if (i < Nn) Sr[i] = 1.0 / Sr[i];
  if (i < Mm) Sc[i] = 1.0 / Sc[i];
}

// ---------------------------------------------------------------------------
// Pass 2: 128x64 tile, 256 thr, 8x4/thread. Peak live regs ~100 < 128 ->
// no scratch spill even when the allocator caps at 128 (R2/R5 behavior).
// Per-element chains bitwise identical to R5 (tile shape reassigns elements
// to threads but never reorders an element's own op sequence).
// ---------------------------------------------------------------------------
__global__ __launch_bounds__(256, 3) void k_pass2(
    const float* __restrict__ A, const float* __restrict__ B,
    const float* __restrict__ C0, const float* __restrict__ C1,
    const double* __restrict__ invSr, const double* __restrict__ invSc,
    uint2* __restrict__ cand, unsigned int* __restrict__ ctr, unsigned int cap) {
  __shared__ float SA[TK][BT];   // A / C0 staging (128 wide)
  __shared__ float SB[TK][BM2];  // B / C1 staging (64 wide)
  __shared__ unsigned int h1[256];
  __shared__ unsigned int scn[256];
  __shared__ unsigned int sh_misc[4];
  const int tid = threadIdx.x;
  const int tx = tid & 15, ty = tid >> 4;
  const int n0 = blockIdx.y * BT, m0 = blockIdx.x * BM2;

  // ---- inner GEMM (two-level, i-split) ----
  float acc2[8][4];
#pragma unroll
  for (int i = 0; i < 8; ++i)
#pragma unroll
    for (int j = 0; j < 4; ++j) acc2[i][j] = 0.0f;
  {
    const int arow = tid >> 1;       // 0..127
    const int ak8  = (tid & 1) * 8;  // 0 or 8
    const int brow = tid >> 2;       // 0..63
    const int bk4  = (tid & 3) * 4;  // 0,4,8,12
    const float* Ap = A + (size_t)(n0 + arow) * Dd + ak8;
    const float* Bp = B + (size_t)(m0 + brow) * Dd + bk4;
    float4 pa0 = *(const float4*)(Ap);
    float4 pa1 = *(const float4*)(Ap + 4);
    float4 pb  = *(const float4*)(Bp);
    for (int k0 = 0; k0 < Dd; k0 += TK) {
      __syncthreads();
      {
        const float ar[8] = {pa0.x,pa0.y,pa0.z,pa0.w,pa1.x,pa1.y,pa1.z,pa1.w};
#pragma unroll
        for (int s = 0; s < 8; ++s) SA[ak8 + s][arow] = ar[s];
        SB[bk4 + 0][brow] = pb.x; SB[bk4 + 1][brow] = pb.y;
        SB[bk4 + 2][brow] = pb.z; SB[bk4 + 3][brow] = pb.w;
      }
      if (k0 + TK < Dd) {
        pa0 = *(const float4*)(Ap + k0 + TK);
        pa1 = *(const float4*)(Ap + k0 + TK + 4);
        pb  = *(const float4*)(Bp + k0 + TK);
      }
      __syncthreads();
#pragma unroll
      for (int h = 0; h < 2; ++h) {
        float t[4][4];
#pragma unroll
        for (int i = 0; i < 4; ++i)
#pragma unroll
          for (int j = 0; j < 4; ++j) t[i][j] = 0.0f;
#pragma unroll
        for (int kk = 0; kk < TK; ++kk) {
          const float4 av  = *(const float4*)&SA[kk][ty * 8 + h * 4];
          const float2 bv0 = *(const float2*)&SB[kk][tx * 2];
          const float2 bv1 = *(const float2*)&SB[kk][32 + tx * 2];
          const float a[4] = {av.x, av.y, av.z, av.w};
          const float b[4] = {bv0.x, bv0.y, bv1.x, bv1.y};
#pragma unroll
          for (int i = 0; i < 4; ++i)
#pragma unroll
            for (int j = 0; j < 4; ++j) t[i][j] = fmaf(a[i], b[j], t[i][j]);
        }
#pragma unroll
        for (int i = 0; i < 4; ++i)
#pragma unroll
          for (int j = 0; j < 4; ++j) acc2[h * 4 + i][j] += t[i][j];
      }
    }
  }

  // ---- overlap GEMM (cas0:[C][N] x cas1:[C][M]) ----
  float ov2[8][4];
#pragma unroll
  for (int i = 0; i < 8; ++i)
#pragma unroll
    for (int j = 0; j < 4; ++j) ov2[i][j] = 0.0f;
  {
    const int fc = tid >> 5;          // 0..7 (rows fc, fc+8)
    const int fn = (tid & 31) * 4;
    const int gc = tid >> 4;          // 0..15
    const int gn = (tid & 15) * 4;
    const float* c0a = C0 + (size_t)fc * Nn + n0 + fn;
    const float* c0b = C0 + (size_t)(fc + 8) * Nn + n0 + fn;
    const float* c1p = C1 + (size_t)gc * Mm + m0 + gn;
    float4 pa0 = *(const float4*)c0a;
    float4 pa1 = *(const float4*)c0b;
    float4 pb  = *(const float4*)c1p;
    for (int c0i = 0; c0i < Cc; c0i += TK) {
      __syncthreads();
      *(float4*)&SA[fc][fn]     = pa0;
      *(float4*)&SA[fc + 8][fn] = pa1;
      *(float4*)&SB[gc][gn]     = pb;
      if (c0i + TK < Cc) {
        pa0 = *(const float4*)(c0a + (size_t)(c0i + TK) * Nn);
        pa1 = *(const float4*)(c0b + (size_t)(c0i + TK) * Nn);
        pb  = *(const float4*)(c1p + (size_t)(c0i + TK) * Mm);
      }
      __syncthreads();
#pragma unroll
      for (int h = 0; h < 2; ++h) {
        float t[4][4];
#pragma unroll
        for (int i = 0; i < 4; ++i)
#pragma unroll
          for (int j = 0; j < 4; ++j) t[i][j] = 0.0f;
#pragma unroll
        for (int kk = 0; kk < TK; ++kk) {
          const float4 av  = *(const float4*)&SA[kk][ty * 8 + h * 4];
          const float2 bv0 = *(const float2*)&SB[kk][tx * 2];
          const float2 bv1 = *(const float2*)&SB[kk][32 + tx * 2];
          const float a[4] = {av.x, av.y, av.z, av.w};
          const float b[4] = {bv0.x, bv0.y, bv1.x, bv1.y};
#pragma unroll
          for (int i = 0; i < 4; ++i)
#pragma unroll
            for (int j = 0; j < 4; ++j) t[i][j] = fmaf(a[i], b[j], t[i][j]);
        }
#pragma unroll
        for (int i = 0; i < 4; ++i)
#pragma unroll
          for (int j = 0; j < 4; ++j) ov2[h * 4 + i][j] += t[i][j];
      }
    }
  }

  // ---- f64 normalizers via LDS (same bits), f64 score -> f32 key ----
  __syncthreads();
  double* dsr = (double*)(&SA[0][0]);   // 128 doubles (1 KB of 8 KB)
  double* dsc = (double*)(&SB[0][0]);   // 64 doubles (512 B of 4 KB)
  if (tid < BT)  dsr[tid] = invSr[n0 + tid];
  if (tid < BM2) dsc[tid] = invSc[m0 + tid];
  __syncthreads();

  unsigned int sbits[8][4];
#pragma unroll
  for (int i = 0; i < 8; ++i)
#pragma unroll
    for (int j = 0; j < 4; ++j) {
      const double e = exp(2.0 * (double)acc2[i][j] - 2.0);
      const double s = e * e * dsr[ty * 8 + i] * dsc[jcol4(tx, j)] * (double)ov2[i][j];
      sbits[i][j] = __float_as_uint((float)s);  // s > 0 -> monotone bits
    }

  // ---- two-level (8+8 bit) block histogram threshold over 8192 elems ----
  h1[tid] = 0;
  __syncthreads();
#pragma unroll
  for (int i = 0; i < 8; ++i)
#pragma unroll
    for (int j = 0; j < 4; ++j) atomicAdd(&h1[sbits[i][j] >> 24], 1u);
  __syncthreads();
  if (tid == 0) {
    unsigned cum = 0, cb = 0, above = 0;
    for (int b = 255; b >= 0; --b) {
      const unsigned nc = cum + h1[b];
      if (nc >= 256u) { cb = (unsigned)b; above = cum; break; }
      cum = nc;
    }
    sh_misc[0] = cb; sh_misc[1] = above;
  }
  __syncthreads();
  const unsigned cb = sh_misc[0], above = sh_misc[1];
  __syncthreads();
  h1[tid] = 0;
  __syncthreads();
#pragma unroll
  for (int i = 0; i < 8; ++i)
#pragma unroll
    for (int j = 0; j < 4; ++j)
      if ((sbits[i][j] >> 24) == cb) atomicAdd(&h1[(sbits[i][j] >> 16) & 0xFFu], 1u);
  __syncthreads();
  if (tid == 0) {
    unsigned cum = above, tb = cb << 8;
    for (int b = 255; b >= 0; --b) {
      cum += h1[b];
      if (cum >= 256u) { tb = (cb << 8) | (unsigned)b; break; }
    }
    const unsigned old = atomicMax(&ctr[2], tb);  // device-scope running bound
    sh_misc[2] = tb > old ? tb : old;
  }
  __syncthreads();
  const unsigned tb16 = sh_misc[2];

  // ---- candidate push (block-aggregated offsets) ----
  unsigned cnt = 0;
#pragma unroll
  for (int i = 0; i < 8; ++i)
#pragma unroll
    for (int j = 0; j < 4; ++j) cnt += ((sbits[i][j] >> 16) >= tb16) ? 1u : 0u;
  scn[tid] = cnt;
  __syncthreads();
  if (tid == 0) {
    unsigned run = 0;
    for (int t = 0; t < 256; ++t) { const unsigned c = scn[t]; scn[t] = run; run += c; }
    sh_misc[3] = atomicAdd(&ctr[0], run);
  }
  __syncthreads();
  unsigned pos = sh_misc[3] + scn[tid];
#pragma unroll
  for (int i = 0; i < 8; ++i)
#pragma unroll
    for (int j = 0; j < 4; ++j) {
      if ((sbits[i][j] >> 16) >= tb16) {
        if (pos < cap) {
          const unsigned idxv = ((unsigned)(n0 + ty * 8 + i) << 13) | (unsigned)(m0 + jcol4(tx, j));
          cand[pos] = make_uint2(sbits[i][j], idxv);
        }
        ++pos;
      }
    }
}

// ---------------------------------------------------------------------------
// Tail: LDS-aggregated coarse(8b) + fine(8b) histograms -> threshold -> collect
// -> sort. Avoids the contended 65536-bin global-atomic histogram.
// ---------------------------------------------------------------------------
__global__ __launch_bounds__(256) void k_histc(const uint2* __restrict__ cand,
                                               const unsigned int* __restrict__ ctr,
                                               unsigned int cap,
                                               unsigned int* __restrict__ ghc) {
  __shared__ unsigned int lh[256];
  const int tid = threadIdx.x;
  lh[tid] = 0;
  __syncthreads();
  const unsigned n = min(ctr[0], cap);
  const unsigned stride = gridDim.x * blockDim.x;
  for (unsigned i = blockIdx.x * blockDim.x + tid; i < n; i += stride)
    atomicAdd(&lh[cand[i].x >> 24], 1u);
  __syncthreads();
  if (lh[tid]) atomicAdd(&ghc[tid], lh[tid]);
}

__global__ __launch_bounds__(256) void k_threshc(const unsigned int* __restrict__ ghc,
                                                 unsigned int* __restrict__ ctr) {
  __shared__ unsigned int g[256];
  const int tid = threadIdx.x;
  g[tid] = ghc[tid];
  __syncthreads();
  if (tid == 0) {
    unsigned cum = 0;
    for (int b = 255; b >= 0; --b) {
      cum += g[b];
      if (cum >= 256u) { ctr[4] = (unsigned)b; ctr[5] = cum - g[b]; break; }
    }
  }
}

__global__ __launch_bounds__(256) void k_histf(const uint2* __restrict__ cand,
                                               const unsigned int* __restrict__ ctr,
                                               unsigned int cap,
                                               unsigned int* __restrict__ ghf) {
  __shared__ unsigned int lh[256];
  const int tid = threadIdx.x;
  lh[tid] = 0;
  __syncthreads();
  const unsigned n = min(ctr[0], cap);
  const unsigned cb = ctr[4];
  const unsigned stride = gridDim.x * blockDim.x;
  for (unsigned i = blockIdx.x * blockDim.x + tid; i < n; i += stride) {
    const unsigned k = cand[i].x;
    if ((k >> 24) == cb) atomicAdd(&lh[(k >> 16) & 0xFFu], 1u);
  }
  __syncthreads();
  if (lh[tid]) atomicAdd(&ghf[tid], lh[tid]);
}

__global__ __launch_bounds__(256) void k_threshf(const unsigned int* __restrict__ ghf,
                                                 unsigned int* __restrict__ ctr) {
  __shared__ unsigned int g[256];
  const int tid = threadIdx.x;
  g[tid] = ghf[tid];
  __syncthreads();
  if (tid == 0) {
    const unsigned cb = ctr[4];
    unsigned cum = ctr[5], tb = cb << 8;
    for (int b = 255; b >= 0; --b) {
      cum += g[b];
      if (cum >= 256u) { tb = (cb << 8) | (unsigned)b; break; }
    }
    ctr[3] = tb;
  }
}

__global__ void k_collect(const uint2* __restrict__ cand,
                          unsigned int* __restrict__ ctr,
                          unsigned int cap, uint2* __restrict__ fin) {
  const unsigned n = min(ctr[0], cap);
  const unsigned tb = ctr[3];
  const unsigned stride = gridDim.x * blockDim.x;
  for (unsigned i = blockIdx.x * blockDim.x + threadIdx.x; i < n; i += stride) {
    const uint2 c = cand[i];
    if ((c.x >> 16) >= tb) {
      const unsigned p = atomicAdd(&ctr[1], 1u);
      if (p < FCAP) fin[p] = c;
    }
  }
}

// Sort: pack (key, ~idx) into u64, bitonic desc -> (key desc, idx asc) —
// exactly lax.top_k / np tie semantics on the f32 scores.
__global__ __launch_bounds__(256) void k_sort(const uint2* __restrict__ fin,
                                              const unsigned int* __restrict__ ctr,
                                              float* __restrict__ out) {
  __shared__ unsigned long long kk[FCAP];
  const int tid = threadIdx.x;
  const unsigned n = min(ctr[1], FCAP);
  unsigned np2 = 256;
  while (np2 < n) np2 <<= 1;
  for (unsigned i = tid; i < np2; i += 256) {
    if (i < n) {
      const uint2 c = fin[i];
      kk[i] = ((unsigned long long)c.x << 32) | (unsigned long long)(c.y ^ 0xFFFFFFFFu);
    } else {
      kk[i] = 0ull;
    }
  }
  __syncthreads();
  for (unsigned k2 = 2; k2 <= np2; k2 <<= 1) {
    for (unsigned j = k2 >> 1; j > 0; j >>= 1) {
      for (unsigned i = tid; i < np2; i += 256) {
        const unsigned l = i ^ j;
        if (l > i) {
          const unsigned long long ka = kk[i], kb = kk[l];
          const bool aBefore = ka > kb;
          const bool dsc = (i & k2) == 0;
          const bool sw = dsc ? !aBefore : aBefore;
          if (sw) { kk[i] = kb; kk[l] = ka; }
        }
      }
      __syncthreads();
    }
  }
  {
    const unsigned long long kv = kk[tid];
    const unsigned key = (unsigned)(kv >> 32);
    const unsigned ix  = ((unsigned)kv) ^ 0xFFFFFFFFu;
    out[tid]        = (float)(ix >> 13);      // ref_corr_indices
    out[256 + tid]  = (float)(ix & 8191u);    // src_corr_indices
    out[512 + tid]  = __uint_as_float(key);   // corr_scores (same f32 bits)
  }
}

// ---------------------------------------------------------------------------
extern "C" void kernel_launch(void* const* d_in, const int* in_sizes, int n_in,
                              void* d_out, int out_size, void* d_ws, size_t ws_size,
                              hipStream_t stream) {
  (void)in_sizes; (void)n_in; (void)out_size;
  const float* ref = (const float*)d_in[0];
  const float* src = (const float*)d_in[1];
  const float* c0  = (const float*)d_in[2];
  const float* c1  = (const float*)d_in[3];
  char* ws = (char*)d_ws;
  double* Sr = (double*)(ws + WS_SR);
  double* Sc = (double*)(ws + WS_SC);
  unsigned int* ctr = (unsigned int*)(ws + WS_CTR);
  unsigned int* ghc = (unsigned int*)(ws + WS_GHC);
  unsigned int* ghf = (unsigned int*)(ws + WS_GHF);
  uint2* fin  = (uint2*)(ws + WS_FINAL);
  uint2* cand = (uint2*)(ws + WS_CAND);
  const unsigned int cap = (ws_size > WS_CAND + 8)
      ? (unsigned int)std::min<size_t>((ws_size - WS_CAND) / 8, (size_t)(16u << 20))
      : 0u;

  hipMemsetAsync(d_ws, 0, (size_t)WS_FINAL, stream);  // Sr, Sc, ctr, ghc, ghf

  dim3 g1(Mm / BT, Nn / BT);
  dim3 g2(Mm / BM2, Nn / BT);
  k_pass1<<<g1, 256, 0, stream>>>(ref, src, Sr, Sc);
  k_recip<<<32, 256, 0, stream>>>(Sr, Sc);
  k_pass2<<<g2, 256, 0, stream>>>(ref, src, c0, c1, Sr, Sc, cand, ctr, cap);
  k_histc<<<256, 256, 0, stream>>>(cand, ctr, cap, ghc);
  k_threshc<<<1, 256, 0, stream>>>(ghc, ctr);
  k_histf<<<256, 256, 0, stream>>>(cand, ctr, cap, ghf);
  k_threshf<<<1, 256, 0, stream>>>(ghf, ctr);
  k_collect<<<256, 256, 0, stream>>>(cand, ctr, cap, fin);
  k_sort<<<1, 256, 0, stream>>>(fin, ctr, (float*)d_out);
}